// Round 5
// baseline (361.739 us; speedup 1.0000x reference)
//
#include <hip/hip_runtime.h>
#include <hip/hip_bf16.h>

#define TDIM 384
#define HID 150
#define DD 128
#define ROWS 81920          // 16384 * 5
#define RT 16               // rows per block (1 wave per block)
#define NREP 32             // Sglob replication

typedef __attribute__((ext_vector_type(8))) short short8;
typedef __attribute__((ext_vector_type(4))) float f32x4;

// LDS byte map (aliased phases, single wave -> no barriers):
//  GEMM2 : Hs[16][168] bf16 @0 ( 5376)
//  Tail  : Ts[16][132] f32  @0 ( 8448)
#define SMEM_BYTES 8448

__device__ __forceinline__ float lrelu(float x) { return x > 0.f ? x : 0.01f * x; }
__device__ __forceinline__ float softplusf(float x) {
    return fmaxf(x, 0.f) + log1pf(expf(-fabsf(x)));
}

__device__ __forceinline__ short8 pack8(const float4 a, const float4 b) {
    union { short8 s; __hip_bfloat16 h[8]; } u;
    u.h[0] = __float2bfloat16(a.x); u.h[1] = __float2bfloat16(a.y);
    u.h[2] = __float2bfloat16(a.z); u.h[3] = __float2bfloat16(a.w);
    u.h[4] = __float2bfloat16(b.x); u.h[5] = __float2bfloat16(b.y);
    u.h[6] = __float2bfloat16(b.z); u.h[7] = __float2bfloat16(b.w);
    return u.s;
}

// =============== K0: prepack w1/w2 -> wave-coalesced fragment order ===============
// w1fT flat = kt*640 + jj*64 + lane   (jj 0..9):  col = jj*16 + m16, k = kt*32 + quad*8
// w2fT flat = kt*512 + jj*64 + lane   (jj 0..7):  col = jj*16 + m16, k = kt*32 + quad*8
// => each per-jj fragment load reads 64 CONSECUTIVE short8 (1 KB contiguous).
__global__ __launch_bounds__(256)
void prep_w(const float* __restrict__ w1, const float* __restrict__ w2,
            short8* __restrict__ w1fT, short8* __restrict__ w2fT)
{
    const int idx = blockIdx.x * 256 + threadIdx.x;
    union { short8 s; __hip_bfloat16 h[8]; } u;
    if (idx < 7680) {
        const int kt  = idx / 640;
        const int rem = idx % 640;
        const int jj  = rem / 64;
        const int ln  = rem % 64;
        const int quad = ln >> 4, m16 = ln & 15;
        const int col = jj * 16 + m16;
        const int k   = kt * 32 + quad * 8;
#pragma unroll
        for (int j = 0; j < 8; ++j)
            u.h[j] = __float2bfloat16(col < HID ? w1[(size_t)col * TDIM + k + j] : 0.f);
        w1fT[idx] = u.s;
    } else if (idx < 10240) {
        const int i2  = idx - 7680;
        const int kt  = i2 / 512;
        const int rem = i2 % 512;
        const int jj  = rem / 64;
        const int ln  = rem % 64;
        const int quad = ln >> 4, m16 = ln & 15;
        const int col = jj * 16 + m16;
        const int k   = kt * 32 + quad * 8;
#pragma unroll
        for (int j = 0; j < 8; ++j)
            u.h[j] = __float2bfloat16((k + j) < HID ? w2[(size_t)col * HID + k + j] : 0.f);
        w2fT[i2] = u.s;
    }
}

// =============== K1: fused, 1 wave per block, barrier-free ===============
__global__ __launch_bounds__(64, 4)
void fused_main(const int* __restrict__ batch,
                const float* __restrict__ text,
                const float* __restrict__ user_table,
                const float* __restrict__ item_table,
                const short8* __restrict__ w1fT,
                const float* __restrict__ b1,
                const short8* __restrict__ w2fT,
                const float* __restrict__ b2,
                const float* __restrict__ aw1,
                const float* __restrict__ ab1,
                const float* __restrict__ aw2,
                float* __restrict__ expp,
                float* __restrict__ Sglob)
{
    __shared__ __align__(16) unsigned char smem[SMEM_BYTES];
    __shared__ __align__(8) float red[RT * 8];   // [row 16][f 4][c 2]
    __hip_bfloat16* Hs = (__hip_bfloat16*)(smem);
    float*          Ts = (float*)(smem);

    const int lane = threadIdx.x;       // 0..63
    const int r0   = blockIdx.x * RT;
    const int m16  = lane & 15;
    const int quad = lane >> 4;
    const int ko0  = quad * 8;

    // tail decomposition: 4 threads per row, one f each
    const int p3row = lane >> 2;
    const int p3f   = lane & 3;
    const int gr    = r0 + p3row;
    const int bb    = gr / 5;
    const int nn    = gr - bb * 5;

    // issue index loads early (latency hidden under GEMM1)
    const int uid = batch[bb * 6];
    const int iid = batch[bb * 6 + 1 + nn];

    // ---------------- GEMM1: M=16 N=160(150) K=384 ----------------
    const float* ta = text + (size_t)(r0 + m16) * TDIM;

    f32x4 acc1[10];
#pragma unroll
    for (int j = 0; j < 10; ++j) acc1[j] = (f32x4){0.f, 0.f, 0.f, 0.f};

    float4 pA[2][2];
#pragma unroll
    for (int k = 0; k < 2; ++k) {
        pA[k][0] = *(const float4*)(ta + k * 32 + ko0);
        pA[k][1] = *(const float4*)(ta + k * 32 + ko0 + 4);
    }

#pragma unroll
    for (int kt = 0; kt < 12; ++kt) {
        const int p = kt & 1;
        short8 bw[10];
#pragma unroll
        for (int jj = 0; jj < 10; ++jj)
            bw[jj] = w1fT[kt * 640 + jj * 64 + lane];
        const short8 a0 = pack8(pA[p][0], pA[p][1]);
        if (kt < 10) {
            const int ko = (kt + 2) * 32 + ko0;
            pA[p][0] = *(const float4*)(ta + ko);
            pA[p][1] = *(const float4*)(ta + ko + 4);
        }
#pragma unroll
        for (int jj = 0; jj < 10; ++jj)
            acc1[jj] = __builtin_amdgcn_mfma_f32_16x16x32_bf16(a0, bw[jj], acc1[jj], 0, 0, 0);
    }

    // ---------------- epilogue1 -> Hs bf16 (cols >= HID zeroed) ----------------
#pragma unroll
    for (int jj = 0; jj < 10; ++jj) {
        const int col = jj * 16 + m16;
        const float bv = (col < HID) ? b1[col] : 0.f;
#pragma unroll
        for (int r = 0; r < 4; ++r) {
            const int row = quad * 4 + r;
            float v = lrelu(acc1[jj][r] + bv);
            if (col >= HID) v = 0.f;
            Hs[row * 168 + col] = __float2bfloat16(v);
        }
    }
    // single wave: compiler-inserted lgkmcnt orders Hs writes before reads

    // ---------------- GEMM2: M=16 N=128 K=160(150) ----------------
    f32x4 acc2[8];
#pragma unroll
    for (int j = 0; j < 8; ++j) acc2[j] = (f32x4){0.f, 0.f, 0.f, 0.f};

    const __hip_bfloat16* h0p = Hs + m16 * 168 + ko0;

#pragma unroll
    for (int kt = 0; kt < 5; ++kt) {
        short8 cw[8];
#pragma unroll
        for (int jj = 0; jj < 8; ++jj)
            cw[jj] = w2fT[kt * 512 + jj * 64 + lane];
        const short8 a0 = *(const short8*)(h0p + kt * 32);
#pragma unroll
        for (int jj = 0; jj < 8; ++jj)
            acc2[jj] = __builtin_amdgcn_mfma_f32_16x16x32_bf16(a0, cw[jj], acc2[jj], 0, 0, 0);
    }

    // ---- issue gathers (hide HBM/L3 latency under epilogue2 LDS work) ----
    const float* up = user_table + (size_t)uid * DD + p3f * 32;
    const float* ip = item_table + (size_t)iid * DD + p3f * 32;
    float4 ur[8], er[8];
#pragma unroll
    for (int q = 0; q < 8; ++q) {
        ur[q] = *(const float4*)(up + q * 4);
        er[q] = *(const float4*)(ip + q * 4);
    }

    // ---- epilogue2 -> Ts fp32 in LDS (aliases Hs; same-wave ordering) ----
#pragma unroll
    for (int jj = 0; jj < 8; ++jj) {
        const int col = jj * 16 + m16;
        const float bv = b2[col];
#pragma unroll
        for (int r = 0; r < 4; ++r) {
            const int row = quad * 4 + r;
            Ts[row * 132 + col] = lrelu(acc2[jj][r] + bv);
        }
    }

    // ---------------- Tail (1 thread per (row,f), full 32-float span) --------
    {
        const float* tp  = Ts + p3row * 132 + p3f * 32;
        const float* a1p = aw1 + p3f * 192;

        float ss = 0.f, z0 = 0.f, z1 = 0.f, sui = 0.f, sut = 0.f;
#pragma unroll
        for (int q = 0; q < 8; ++q) {
            const float4 u4 = ur[q];
            const float4 e4 = er[q];
            const float4 t4 = *(const float4*)(tp + q * 4);
            const float4 a00 = *(const float4*)(a1p + q * 4);
            const float4 a01 = *(const float4*)(a1p + 32 + q * 4);
            const float4 a02 = *(const float4*)(a1p + 64 + q * 4);
            const float4 a10 = *(const float4*)(a1p + 96 + q * 4);
            const float4 a11 = *(const float4*)(a1p + 128 + q * 4);
            const float4 a12 = *(const float4*)(a1p + 160 + q * 4);
            const float uu[4] = {u4.x, u4.y, u4.z, u4.w};
            const float ee[4] = {e4.x, e4.y, e4.z, e4.w};
            const float tt[4] = {t4.x, t4.y, t4.z, t4.w};
            const float w00[4] = {a00.x, a00.y, a00.z, a00.w};
            const float w01[4] = {a01.x, a01.y, a01.z, a01.w};
            const float w02[4] = {a02.x, a02.y, a02.z, a02.w};
            const float w10[4] = {a10.x, a10.y, a10.z, a10.w};
            const float w11[4] = {a11.x, a11.y, a11.z, a11.w};
            const float w12[4] = {a12.x, a12.y, a12.z, a12.w};
#pragma unroll
            for (int c = 0; c < 4; ++c) {
                const float u = uu[c], e = ee[c], x = tt[c];
                ss  = fmaf(u, u, ss); ss = fmaf(e, e, ss); ss = fmaf(x, x, ss);
                z0  = fmaf(u, w00[c], z0);
                z0  = fmaf(e, w01[c], z0);
                z0  = fmaf(x, w02[c], z0);
                z1  = fmaf(u, w10[c], z1);
                z1  = fmaf(e, w11[c], z1);
                z1  = fmaf(x, w12[c], z1);
                sui = fmaf(u, e, sui);
                sut = fmaf(u, x, sut);
            }
        }
        const float inv = 1.f / fmaxf(sqrtf(ss), 1e-12f);
        const float h0 = tanhf(fmaf(z0, inv, ab1[p3f * 2 + 0]));
        const float h1 = tanhf(fmaf(z1, inv, ab1[p3f * 2 + 1]));
        const float l0 = fmaf(h0, aw2[p3f * 4 + 0], h1 * aw2[p3f * 4 + 1]);
        const float l1 = fmaf(h0, aw2[p3f * 4 + 2], h1 * aw2[p3f * 4 + 3]);
        const float e0 = expf(l0), e1 = expf(l1);
        const float pui = softplusf(sui), put = softplusf(sut);
        *(float4*)&expp[((size_t)gr * 4 + p3f) * 4] = make_float4(e0, e1, pui, put);
        *(float2*)&red[p3row * 8 + p3f * 2] = make_float2(e0, e1);
    }
    // same-wave LDS ordering; no barrier

    // block reduce -> NREP-way replicated global accumulators
    if (lane < 40) {
        const int j   = lane & 7;     // f*2 + c
        const int nn0 = lane >> 3;    // 0..4
        const int rep = blockIdx.x & (NREP - 1);
        int r = nn0 - (r0 % 5);
        if (r < 0) r += 5;
        float s = 0.f;
        for (; r < RT; r += 5) s += red[r * 8 + j];
        atomicAdd(&Sglob[((size_t)rep * 40 + lane) * 16], s);
    }
}

// =============== K2: ratings ===============
__global__ __launch_bounds__(256)
void finalize(const float* __restrict__ expp,
              const float* __restrict__ Sglob,
              float* __restrict__ out)
{
    __shared__ float Ss[40];
    const int t = threadIdx.x;

    if (t < 40) {
        float s = 0.f;
#pragma unroll
        for (int rep = 0; rep < NREP; ++rep)
            s += Sglob[((size_t)rep * 40 + t) * 16];
        Ss[t] = s;
    }
    __syncthreads();

    const int gr = blockIdx.x * 256 + t;   // grid is exactly ROWS/256 blocks
    const int b = gr / 5;
    const int n = gr - b * 5;
    float r = 0.f;
#pragma unroll
    for (int f = 0; f < 4; ++f) {
        const float4 v = *(const float4*)&expp[((size_t)gr * 4 + f) * 4];
        const float S0 = Ss[n * 8 + f * 2 + 0];
        const float S1 = Ss[n * 8 + f * 2 + 1];
        r += v.x / S0 * v.z + v.y / S1 * v.w;
    }
    out[gr] = r;
}

extern "C" void kernel_launch(void* const* d_in, const int* in_sizes, int n_in,
                              void* d_out, int out_size, void* d_ws, size_t ws_size,
                              hipStream_t stream)
{
    (void)in_sizes; (void)n_in; (void)out_size; (void)ws_size;
    const int*   batch      = (const int*)d_in[0];
    const float* text       = (const float*)d_in[1];
    const float* user_table = (const float*)d_in[2];
    const float* item_table = (const float*)d_in[3];
    const float* w1         = (const float*)d_in[4];
    const float* b1         = (const float*)d_in[5];
    const float* w2         = (const float*)d_in[6];
    const float* b2         = (const float*)d_in[7];
    const float* aw1        = (const float*)d_in[8];
    const float* ab1        = (const float*)d_in[9];
    const float* aw2        = (const float*)d_in[10];
    float* out = (float*)d_out;

    char* ws = (char*)d_ws;
    short8* w1fT  = (short8*)ws;                        // 7680*16  = 122880 B
    short8* w2fT  = (short8*)(ws + 122880);             // 2560*16  =  40960 B
    float*  expp  = (float*)(ws + 163840);              // ROWS*16 f32 = 5.24 MB
    float*  Sglob = (float*)(ws + 163840 + (size_t)ROWS * 16 * 4);  // NREP*40*16 f32

    hipMemsetAsync(Sglob, 0, (size_t)NREP * 40 * 16 * sizeof(float), stream);
    prep_w<<<40, 256, 0, stream>>>(w1, w2, w1fT, w2fT);
    fused_main<<<ROWS / RT, 64, 0, stream>>>(batch, text, user_table, item_table,
                                             w1fT, b1, w2fT, b2, aw1, ab1, aw2,
                                             expp, Sglob);
    finalize<<<ROWS / 256, 256, 0, stream>>>(expp, Sglob, out);
}

// Round 7
// 300.877 us; speedup vs baseline: 1.2023x; 1.2023x over previous
//
#include <hip/hip_runtime.h>
#include <hip/hip_bf16.h>

#define TDIM 384
#define HID 150
#define DD 128
#define ROWS 81920          // 16384 * 5
#define RT 32               // rows per block

typedef __attribute__((ext_vector_type(8))) short short8;
typedef __attribute__((ext_vector_type(4))) float f32x4;

// LDS byte map (aliased phases):
//  Stage/GEMM1 : tA[32][392] bf16 @0      (25088)  padded row stride 784 B
//  GEMM2       : Hs[32][168] bf16 @0      (10752)  (tA dead after GEMM1 barrier)
//  Tail        : Ts[32][132] f32  @0      (16896)
//  red         : f32[32][8]       @16896  ( 1024)
#define SMEM_BYTES 25088
#define TASTRIDE 392

__device__ __forceinline__ float lrelu(float x) { return x > 0.f ? x : 0.01f * x; }
__device__ __forceinline__ float softplusf(float x) {
    return fmaxf(x, 0.f) + log1pf(expf(-fabsf(x)));
}

// =============== K0: prepack w1/w2 -> wave-coalesced fragment order ===============
// w1fT[kt][g][tj][lane]: flat = kt*640 + g*320 + tj*64 + lane
//   lane = quad*16 + m16; col = g*80 + tj*16 + m16; k = kt*32 + quad*8
// w2fT[kt][g][tj][lane]: flat = kt*512 + g*256 + tj*64 + lane
__global__ __launch_bounds__(256)
void prep_w(const float* __restrict__ w1, const float* __restrict__ w2,
            short8* __restrict__ w1fT, short8* __restrict__ w2fT)
{
    const int idx = blockIdx.x * 256 + threadIdx.x;
    union { short8 s; __hip_bfloat16 h[8]; } u;
    if (idx < 7680) {
        const int kt  = idx / 640;
        const int rem = idx % 640;
        const int g   = rem / 320;
        const int r2  = rem % 320;
        const int tj  = r2 / 64;
        const int ln  = r2 % 64;
        const int quad = ln >> 4, m16 = ln & 15;
        const int col = g * 80 + tj * 16 + m16;
        const int k   = kt * 32 + quad * 8;
#pragma unroll
        for (int j = 0; j < 8; ++j)
            u.h[j] = __float2bfloat16(col < HID ? w1[(size_t)col * TDIM + k + j] : 0.f);
        w1fT[idx] = u.s;
    } else if (idx < 10240) {
        const int i2  = idx - 7680;
        const int kt  = i2 / 512;
        const int rem = i2 % 512;
        const int g   = rem / 256;
        const int r2  = rem % 256;
        const int tj  = r2 / 64;
        const int ln  = r2 % 64;
        const int quad = ln >> 4, m16 = ln & 15;
        const int col = g * 64 + tj * 16 + m16;
        const int k   = kt * 32 + quad * 8;
#pragma unroll
        for (int j = 0; j < 8; ++j)
            u.h[j] = __float2bfloat16((k + j) < HID ? w2[(size_t)col * HID + k + j] : 0.f);
        w2fT[i2] = u.s;
    }
}

// =============== K1: fused (round-4 structure + LDS-staged text) ===============
__global__ __launch_bounds__(256, 6)
void fused_main(const int* __restrict__ batch,
                const float* __restrict__ text,
                const float* __restrict__ user_table,
                const float* __restrict__ item_table,
                const short8* __restrict__ w1fT,
                const float* __restrict__ b1,
                const short8* __restrict__ w2fT,
                const float* __restrict__ b2,
                const float* __restrict__ aw1,
                const float* __restrict__ ab1,
                const float* __restrict__ aw2,
                float* __restrict__ expp,
                float* __restrict__ Sglob)
{
    __shared__ __align__(16) unsigned char smem[SMEM_BYTES];
    __hip_bfloat16* tA  = (__hip_bfloat16*)(smem);
    __hip_bfloat16* Hs  = (__hip_bfloat16*)(smem);
    float*          Ts  = (float*)(smem);
    float*          red = (float*)(smem + 16896);

    const int t    = threadIdx.x;
    const int r0   = blockIdx.x * RT;
    const int lane = t & 63;
    const int wv   = t >> 6;
    const int m16  = lane & 15;
    const int quad = lane >> 4;
    const int g    = wv >> 1;             // N-half selector
    const int wr   = (wv & 1) * 16;       // M=32 split 2x16
    const int wc   = g * 80;              // N=160 split 2x80
    const int wc2  = g * 64;              // N=128 split 2x64

    // tail work decomposition: 2 threads per (row, f)
    const int p3row = t >> 3;
    const int p3f   = (t >> 1) & 3;
    const int half  = t & 1;
    const int gr    = r0 + p3row;
    const int bb    = gr / 5;
    const int nn    = gr - bb * 5;

    // ---------------- stage text tile -> LDS bf16 (coalesced) ----------------
    {
        const float* tbase = text + (size_t)r0 * TDIM;   // 48 KB contiguous
#pragma unroll
        for (int i = 0; i < 12; ++i) {
            const int fi  = i * 1024 + t * 4;            // flat float index
            const int row = fi / TDIM;
            const int k   = fi - row * TDIM;             // multiple of 4
            const float4 v = *(const float4*)(tbase + fi);
            union { __hip_bfloat16 h[4]; unsigned long long q; } o;
            o.h[0] = __float2bfloat16(v.x);
            o.h[1] = __float2bfloat16(v.y);
            o.h[2] = __float2bfloat16(v.z);
            o.h[3] = __float2bfloat16(v.w);
            *(unsigned long long*)(tA + row * TASTRIDE + k) = o.q;
        }
    }
    __syncthreads();   // b0: tA ready

    // ---------------- GEMM1: M=32 N=160(150) K=384 ----------------
    const int ko0 = quad * 8;
    const __hip_bfloat16* tAp = tA + (wr + m16) * TASTRIDE + ko0;
    const int w1base = g * 320 + lane;    // + kt*640 + tj*64

    f32x4 acc1[5];
#pragma unroll
    for (int j = 0; j < 5; ++j) acc1[j] = (f32x4){0.f, 0.f, 0.f, 0.f};

#pragma unroll
    for (int kt = 0; kt < 12; ++kt) {
        short8 bw[5];
#pragma unroll
        for (int tj = 0; tj < 5; ++tj)
            bw[tj] = w1fT[kt * 640 + w1base + tj * 64];
        const short8 a0 = *(const short8*)(tAp + kt * 32);   // ds_read_b128
#pragma unroll
        for (int tj = 0; tj < 5; ++tj)
            acc1[tj] = __builtin_amdgcn_mfma_f32_16x16x32_bf16(a0, bw[tj], acc1[tj], 0, 0, 0);
    }
    __syncthreads();   // b0.5: all tA reads done before Hs alias-write

    // ---------------- epilogue1 -> Hs bf16 (cols >= HID zeroed) ----------------
#pragma unroll
    for (int tj = 0; tj < 5; ++tj) {
        const int col = wc + tj * 16 + m16;
        const float bv = (col < HID) ? b1[col] : 0.f;
#pragma unroll
        for (int r = 0; r < 4; ++r) {
            const int row = wr + quad * 4 + r;
            float v = lrelu(acc1[tj][r] + bv);
            if (col >= HID) v = 0.f;
            Hs[row * 168 + col] = __float2bfloat16(v);
        }
    }
    __syncthreads();   // b1: Hs ready

    // ---------------- GEMM2: M=32 N=128 K=160(150) ----------------
    f32x4 acc2[4];
#pragma unroll
    for (int j = 0; j < 4; ++j) acc2[j] = (f32x4){0.f, 0.f, 0.f, 0.f};

    const __hip_bfloat16* h0p = Hs + (wr + m16) * 168 + ko0;
    const int w2base = g * 256 + lane;    // + kt*512 + tj*64

#pragma unroll
    for (int kt = 0; kt < 5; ++kt) {
        short8 bw[4];
#pragma unroll
        for (int tj = 0; tj < 4; ++tj)
            bw[tj] = w2fT[kt * 512 + w2base + tj * 64];
        const short8 a0 = *(const short8*)(h0p + kt * 32);
#pragma unroll
        for (int tj = 0; tj < 4; ++tj)
            acc2[tj] = __builtin_amdgcn_mfma_f32_16x16x32_bf16(a0, bw[tj], acc2[tj], 0, 0, 0);
    }
    __syncthreads();   // b2: Hs reads done before Ts alias-write

    // ---- epilogue2 -> Ts fp32 in LDS ----
#pragma unroll
    for (int tj = 0; tj < 4; ++tj) {
        const int col = wc2 + tj * 16 + m16;
        const float bv = b2[col];
#pragma unroll
        for (int r = 0; r < 4; ++r) {
            const int row = wr + quad * 4 + r;
            Ts[row * 132 + col] = lrelu(acc2[tj][r] + bv);
        }
    }

    // ---- issue gathers (acc2 dead; latency hides under barrier) ----
    const int uid = batch[bb * 6];
    const int iid = batch[bb * 6 + 1 + nn];
    const float* up = user_table + (size_t)uid * DD + p3f * 32 + half * 16;
    const float* ip = item_table + (size_t)iid * DD + p3f * 32 + half * 16;
    float4 ur[4], er[4];
#pragma unroll
    for (int q = 0; q < 4; ++q) {
        ur[q] = *(const float4*)(up + q * 4);
        er[q] = *(const float4*)(ip + q * 4);
    }
    __syncthreads();   // b3: Ts ready

    // ---------------- Tail (2 threads per (row,f), halves combined by shfl) ----
    {
        const float* tp  = Ts + p3row * 132 + p3f * 32 + half * 16;
        const float* a1p = aw1 + p3f * 192 + half * 16;

        float ss = 0.f, z0 = 0.f, z1 = 0.f, sui = 0.f, sut = 0.f;
#pragma unroll
        for (int q = 0; q < 4; ++q) {
            const float4 u4 = ur[q];
            const float4 e4 = er[q];
            const float4 t4 = *(const float4*)(tp + q * 4);
            const float4 a00 = *(const float4*)(a1p + q * 4);
            const float4 a01 = *(const float4*)(a1p + 32 + q * 4);
            const float4 a02 = *(const float4*)(a1p + 64 + q * 4);
            const float4 a10 = *(const float4*)(a1p + 96 + q * 4);
            const float4 a11 = *(const float4*)(a1p + 128 + q * 4);
            const float4 a12 = *(const float4*)(a1p + 160 + q * 4);
            const float uu[4] = {u4.x, u4.y, u4.z, u4.w};
            const float ee[4] = {e4.x, e4.y, e4.z, e4.w};
            const float tt[4] = {t4.x, t4.y, t4.z, t4.w};
            const float w00[4] = {a00.x, a00.y, a00.z, a00.w};
            const float w01[4] = {a01.x, a01.y, a01.z, a01.w};
            const float w02[4] = {a02.x, a02.y, a02.z, a02.w};
            const float w10[4] = {a10.x, a10.y, a10.z, a10.w};
            const float w11[4] = {a11.x, a11.y, a11.z, a11.w};
            const float w12[4] = {a12.x, a12.y, a12.z, a12.w};
#pragma unroll
            for (int c = 0; c < 4; ++c) {
                const float u = uu[c], e = ee[c], x = tt[c];
                ss  = fmaf(u, u, ss); ss = fmaf(e, e, ss); ss = fmaf(x, x, ss);
                z0  = fmaf(u, w00[c], z0);
                z0  = fmaf(e, w01[c], z0);
                z0  = fmaf(x, w02[c], z0);
                z1  = fmaf(u, w10[c], z1);
                z1  = fmaf(e, w11[c], z1);
                z1  = fmaf(x, w12[c], z1);
                sui = fmaf(u, e, sui);
                sut = fmaf(u, x, sut);
            }
        }
        // combine the two halves (lanes t and t^1, same wave)
        ss  += __shfl_xor(ss, 1);
        z0  += __shfl_xor(z0, 1);
        z1  += __shfl_xor(z1, 1);
        sui += __shfl_xor(sui, 1);
        sut += __shfl_xor(sut, 1);

        const float inv = 1.f / fmaxf(sqrtf(ss), 1e-12f);
        const float h0 = tanhf(fmaf(z0, inv, ab1[p3f * 2 + 0]));
        const float h1 = tanhf(fmaf(z1, inv, ab1[p3f * 2 + 1]));
        const float l0 = fmaf(h0, aw2[p3f * 4 + 0], h1 * aw2[p3f * 4 + 1]);
        const float l1 = fmaf(h0, aw2[p3f * 4 + 2], h1 * aw2[p3f * 4 + 3]);
        const float e0 = expf(l0), e1 = expf(l1);
        const float pui = softplusf(sui), put = softplusf(sut);
        if (half == 0) {
            *(float4*)&expp[((size_t)gr * 4 + p3f) * 4] = make_float4(e0, e1, pui, put);
            *(float2*)&red[p3row * 8 + p3f * 2] = make_float2(e0, e1);
        }
    }
    __syncthreads();   // b4: red ready

    // block reduce -> 8-way replicated global accumulators (low contention)
    if (t < 40) {
        const int j   = t & 7;     // f*2 + c
        const int nn0 = t >> 3;    // 0..4
        const int rep = blockIdx.x & 7;
        int r = nn0 - (r0 % 5);
        if (r < 0) r += 5;
        float s = 0.f;
        for (; r < RT; r += 5) s += red[r * 8 + j];
        atomicAdd(&Sglob[((t * 8) + rep) * 16], s);
    }
}

// =============== K2: ratings ===============
__global__ __launch_bounds__(256)
void finalize(const float* __restrict__ expp,
              const float* __restrict__ Sglob,
              float* __restrict__ out)
{
    __shared__ float Ss[40];
    const int t = threadIdx.x;

    if (t < 160) {
        const int cidx = t >> 2;       // 0..39
        const int rp   = t & 3;        // pair of replicas
        float v = Sglob[(cidx * 8 + rp * 2 + 0) * 16]
                + Sglob[(cidx * 8 + rp * 2 + 1) * 16];
        v += __shfl_xor(v, 1);
        v += __shfl_xor(v, 2);
        if (rp == 0) Ss[cidx] = v;
    }
    __syncthreads();

    const int gr = blockIdx.x * 256 + t;   // grid is exactly ROWS/256 blocks
    const int b = gr / 5;
    const int n = gr - b * 5;
    float r = 0.f;
#pragma unroll
    for (int f = 0; f < 4; ++f) {
        const float4 v = *(const float4*)&expp[((size_t)gr * 4 + f) * 4];
        const float S0 = Ss[n * 8 + f * 2 + 0];
        const float S1 = Ss[n * 8 + f * 2 + 1];
        r += v.x / S0 * v.z + v.y / S1 * v.w;
    }
    out[gr] = r;
}

extern "C" void kernel_launch(void* const* d_in, const int* in_sizes, int n_in,
                              void* d_out, int out_size, void* d_ws, size_t ws_size,
                              hipStream_t stream)
{
    (void)in_sizes; (void)n_in; (void)out_size; (void)ws_size;
    const int*   batch      = (const int*)d_in[0];
    const float* text       = (const float*)d_in[1];
    const float* user_table = (const float*)d_in[2];
    const float* item_table = (const float*)d_in[3];
    const float* w1         = (const float*)d_in[4];
    const float* b1         = (const float*)d_in[5];
    const float* w2         = (const float*)d_in[6];
    const float* b2         = (const float*)d_in[7];
    const float* aw1        = (const float*)d_in[8];
    const float* ab1        = (const float*)d_in[9];
    const float* aw2        = (const float*)d_in[10];
    float* out = (float*)d_out;

    char* ws = (char*)d_ws;
    short8* w1fT  = (short8*)ws;                        // 7680*16  = 122880 B
    short8* w2fT  = (short8*)(ws + 122880);             // 2560*16  =  40960 B
    float*  expp  = (float*)(ws + 163840);              // ROWS*16 f32 = 5.24 MB
    float*  Sglob = (float*)(ws + 163840 + (size_t)ROWS * 16 * 4);  // 320*16 f32

    hipMemsetAsync(Sglob, 0, 320 * 16 * sizeof(float), stream);
    prep_w<<<40, 256, 0, stream>>>(w1, w2, w1fT, w2fT);
    fused_main<<<ROWS / RT, 256, 0, stream>>>(batch, text, user_table, item_table,
                                              w1fT, b1, w2fT, b2, aw1, ab1, aw2,
                                              expp, Sglob);
    finalize<<<ROWS / 256, 256, 0, stream>>>(expp, Sglob, out);
}